// Round 16
// baseline (378.850 us; speedup 1.0000x reference)
//
#include <hip/hip_runtime.h>
#include <hip/hip_bf16.h>

#define EPS_NORM 1e-12f
#define EPS_SM   1e-16f
#define SLOT     96        // padded CSR stride; >= any realistic in-degree (Poisson(32))
#define BSH      8         // bucket = 256 consecutive dst nodes
#define BRANGE   256
#define NBMAX    512       // LDS sizing (supports N <= 131072)
#define BCAP     9216      // per-bucket edge capacity: mean 8184, +11 sigma
#define TILE     8192      // edges per partition block (r13 form)
#define GEMM_GRID 1024     // 4 blocks/CU at 33KB LDS

typedef float f32x4 __attribute__((ext_vector_type(4)));
__device__ __forceinline__ float shflx(float x, int m) { return __shfl_xor(x, m); }

// ============ pass 1: partition edges into dst-range buckets (r13 form) ============
__global__ __launch_bounds__(1024) void k_part(const int* __restrict__ src,
        const int* __restrict__ dst, int* __restrict__ gcur, int* __restrict__ part,
        int E, int NB) {
    __shared__ int h[NBMAX];
    __shared__ int c0[NBMAX];
    __shared__ int lo[NBMAX + 1];
    __shared__ int cur[NBMAX];
    __shared__ int gb[NBMAX];
    __shared__ int stage[TILE];
    __shared__ unsigned short sb[TILE];
    int t = threadIdx.x;
    int tile0 = blockIdx.x * TILE;
    int n = E - tile0; if (n > TILE) n = TILE;

    for (int i = t; i < NBMAX; i += 1024) h[i] = 0;
    __syncthreads();
    for (int i = t; i < n; i += 1024)
        atomicAdd(&h[dst[tile0 + i] >> BSH], 1);
    __syncthreads();
    for (int i = t; i < NBMAX; i += 1024) c0[i] = h[i];
    __syncthreads();
    for (int d = 1; d < NBMAX; d <<= 1) {
        int v = (t < NBMAX && t >= d) ? h[t - d] : 0;
        __syncthreads();
        if (t < NBMAX) h[t] += v;
        __syncthreads();
    }
    if (t < NBMAX) { lo[t] = h[t] - c0[t]; cur[t] = h[t] - c0[t]; }
    if (t == 0) lo[NBMAX] = n;
    __syncthreads();
    for (int i = t; i < NB; i += 1024)
        gb[i] = (c0[i] > 0) ? atomicAdd(&gcur[i], c0[i]) : 0;
    __syncthreads();
    for (int i = t; i < n; i += 1024) {
        int d = dst[tile0 + i];
        int s = src[tile0 + i];
        int b = d >> BSH;
        int p = atomicAdd(&cur[b], 1);
        stage[p] = (s << BSH) | (d & (BRANGE - 1));
        sb[p] = (unsigned short)b;
    }
    __syncthreads();
    for (int i = t; i < n; i += 1024) {
        int b = sb[i];
        int gpos = gb[b] + (i - lo[b]);
        if (gpos < BCAP)
            part[b * BCAP + gpos] = stage[i];
    }
}

// ============ pass 2: bucket -> padded CSR (one block per bucket; LDS positions) ============
__global__ __launch_bounds__(1024) void k_csr(const int* __restrict__ part,
        const int* __restrict__ gcur, int* __restrict__ csr, int* __restrict__ deg, int N) {
    __shared__ int cnt[BRANGE];
    int b = blockIdx.x, t = threadIdx.x;
    if (t < BRANGE) cnt[t] = 0;
    __syncthreads();
    int cntE = gcur[b]; if (cntE > BCAP) cntE = BCAP;
    const int* pb = part + b * BCAP;
    int n0 = b << BSH;
    for (int i = t; i < cntE; i += 1024) {
        int v = pb[i];
        int d = v & (BRANGE - 1);
        int s = v >> BSH;
        int p = atomicAdd(&cnt[d], 1);
        if (p < SLOT)
            csr[(size_t)(n0 + d) * SLOT + p] = s;
    }
    __syncthreads();
    if (t < BRANGE && n0 + t < N) deg[n0 + t] = cnt[t];
}

// ======================= h = relu(x @ W1 + b1), + inv-norm of h =======================
// Barrier-free tile loop: W1^T in LDS (33KB -> 4 blocks/CU, 16 waves/CU); x read
// directly from global (streamed once, L1 reuses lines across kq). One (row,col)
// per lane: lane (i2,j) -> row tile*16+wave*4+i2, col j. No xs, no red, no K-split.
__global__ __launch_bounds__(256) void k_gemm1(const float* __restrict__ x,
        const float* __restrict__ W1, const float* __restrict__ b1,
        float* __restrict__ h, float* __restrict__ invn, int N) {
    __shared__ __align__(16) float w1t[16 * 516];   // W1 transposed, pad 512->516
    int t = threadIdx.x;
    for (int g = t; g < 2048; g += 256) {           // stage W1^T once per block
        f32x4 v = *(const f32x4*)(W1 + g * 4);
        int k = g >> 2, c0 = (g & 3) * 4;
        w1t[(c0 + 0) * 516 + k] = v.x;
        w1t[(c0 + 1) * 516 + k] = v.y;
        w1t[(c0 + 2) * 516 + k] = v.z;
        w1t[(c0 + 3) * 516 + k] = v.w;
    }
    __syncthreads();                                // the ONLY barrier

    int wave = t >> 6, lane = t & 63;
    int i2 = lane >> 4, j = lane & 15;
    const float* wrow = w1t + j * 516;
    float bj = b1[j];

    int ntiles = (N + 15) >> 4;
    int per = (ntiles + GEMM_GRID - 1) / GEMM_GRID;
    int t0 = blockIdx.x * per;
    int t1 = t0 + per; if (t1 > ntiles) t1 = ntiles;

    for (int tt = t0; tt < t1; ++tt) {
        int row = (tt << 4) + wave * 4 + i2;
        int rowc = row < N ? row : N - 1;           // clamp keeps loads in bounds
        const float* xr = x + (size_t)rowc * 512;
        float acc0 = 0.f, acc1 = 0.f;               // 2 chains break the dep latency
#pragma unroll 8
        for (int kq = 0; kq < 128; kq += 2) {
            f32x4 xv0 = *(const f32x4*)(xr + kq * 4);
            f32x4 wv0 = *(const f32x4*)(wrow + kq * 4);
            f32x4 xv1 = *(const f32x4*)(xr + kq * 4 + 4);
            f32x4 wv1 = *(const f32x4*)(wrow + kq * 4 + 4);
            acc0 += xv0.x*wv0.x + xv0.y*wv0.y + xv0.z*wv0.z + xv0.w*wv0.w;
            acc1 += xv1.x*wv1.x + xv1.y*wv1.y + xv1.z*wv1.z + xv1.w*wv1.w;
        }
        float val = fmaxf(acc0 + acc1 + bj, 0.f);
        float ss = val * val;                       // norm over the 16 j-lanes
        ss += shflx(ss, 1); ss += shflx(ss, 2);
        ss += shflx(ss, 4); ss += shflx(ss, 8);
        if (row < N) {
            h[(size_t)row * 16 + j] = val;
            if (j == 0) invn[row] = 1.f / fmaxf(sqrtf(ss), EPS_NORM);
        }
    }
}

// ============== fused AGNN layer: 4 lanes/edge, 32 edges/iteration (2 chains) ==============
__global__ __launch_bounds__(256) void k_agnn(const float* __restrict__ f,
        const float* __restrict__ inv, const int* __restrict__ deg,
        const int* __restrict__ csr, const float* __restrict__ beta,
        float* __restrict__ fout, float* __restrict__ invout, int N) {
    int wid = (blockIdx.x * 256 + threadIdx.x) >> 6;
    if (wid >= N) return;
    int lane = threadIdx.x & 63;
    int es = lane >> 2, c = lane & 3;

    const f32x4 fd = *(const f32x4*)(f + (size_t)wid * 16 + c * 4);
    float ivd = inv[wid];
    float b   = beta[0];

    float sd = fd.x*fd.x + fd.y*fd.y + fd.z*fd.z + fd.w*fd.w;
    sd += shflx(sd, 1); sd += shflx(sd, 2);
    float pself = __expf(b * sd * ivd * ivd);
    float bs = b * ivd;

    int dg = deg[wid]; if (dg > SLOT) dg = SLOT;
    int start = wid * SLOT;
    int end   = start + dg;

    float sacc = 0.f;
    f32x4 gacc = {0.f, 0.f, 0.f, 0.f};
    for (int eb = start; eb < end; eb += 32) {
        int  e0 = eb + es,      e1 = eb + es + 16;
        bool v0 = e0 < end,     v1 = e1 < end;
        int  si0 = v0 ? csr[e0] : 0;
        int  si1 = v1 ? csr[e1] : 0;
        float iv0 = inv[si0],   iv1 = inv[si1];
        f32x4 fs0 = *(const f32x4*)(f + (size_t)si0 * 16 + c * 4);
        f32x4 fs1 = *(const f32x4*)(f + (size_t)si1 * 16 + c * 4);
        float d0 = fs0.x*fd.x + fs0.y*fd.y + fs0.z*fd.z + fs0.w*fd.w;
        float d1 = fs1.x*fd.x + fs1.y*fd.y + fs1.z*fd.z + fs1.w*fd.w;
        d0 += shflx(d0, 1); d1 += shflx(d1, 1);
        d0 += shflx(d0, 2); d1 += shflx(d1, 2);
        float p0 = v0 ? __expf(bs * iv0 * d0) : 0.f;
        float p1 = v1 ? __expf(bs * iv1 * d1) : 0.f;
        sacc += p0 + p1;
        gacc.x += p0 * fs0.x + p1 * fs1.x;
        gacc.y += p0 * fs0.y + p1 * fs1.y;
        gacc.z += p0 * fs0.z + p1 * fs1.z;
        gacc.w += p0 * fs0.w + p1 * fs1.w;
    }
#pragma unroll
    for (int m = 4; m <= 32; m <<= 1) {
        sacc   += shflx(sacc, m);
        gacc.x += shflx(gacc.x, m); gacc.y += shflx(gacc.y, m);
        gacc.z += shflx(gacc.z, m); gacc.w += shflx(gacc.w, m);
    }
    float denom = sacc + pself + EPS_SM;
    f32x4 o;
    o.x = (gacc.x + pself * fd.x) / denom;
    o.y = (gacc.y + pself * fd.y) / denom;
    o.z = (gacc.z + pself * fd.z) / denom;
    o.w = (gacc.w + pself * fd.w) / denom;

    float ss = o.x*o.x + o.y*o.y + o.z*o.z + o.w*o.w;
    ss += shflx(ss, 1); ss += shflx(ss, 2);

    if (es == 0) {
        *(f32x4*)(fout + (size_t)wid * 16 + c * 4) = o;
        if (c == 0) invout[wid] = 1.f / fmaxf(sqrtf(ss), EPS_NORM);
    }
}

// ===== layer-3 AGNN with fused classifier: out = softmax(agnn(f) @ W2 + b2) =====
__global__ __launch_bounds__(256) void k_agnn_out(const float* __restrict__ f,
        const float* __restrict__ inv, const int* __restrict__ deg,
        const int* __restrict__ csr, const float* __restrict__ beta,
        const float* __restrict__ W2, const float* __restrict__ b2,
        float* __restrict__ out, int N) {
    __shared__ float w2s[16 * 40];
    __shared__ float b2s[40];
    for (int idx = threadIdx.x; idx < 16 * 40; idx += 256) w2s[idx] = W2[idx];
    if (threadIdx.x < 40) b2s[threadIdx.x] = b2[threadIdx.x];
    __syncthreads();

    int wid = (blockIdx.x * 256 + threadIdx.x) >> 6;
    if (wid >= N) return;
    int lane = threadIdx.x & 63;
    int es = lane >> 2, c = lane & 3;

    const f32x4 fd = *(const f32x4*)(f + (size_t)wid * 16 + c * 4);
    float ivd = inv[wid];
    float b   = beta[0];

    float sd = fd.x*fd.x + fd.y*fd.y + fd.z*fd.z + fd.w*fd.w;
    sd += shflx(sd, 1); sd += shflx(sd, 2);
    float pself = __expf(b * sd * ivd * ivd);
    float bs = b * ivd;

    int dg = deg[wid]; if (dg > SLOT) dg = SLOT;
    int start = wid * SLOT;
    int end   = start + dg;

    float sacc = 0.f;
    f32x4 gacc = {0.f, 0.f, 0.f, 0.f};
    for (int eb = start; eb < end; eb += 32) {
        int  e0 = eb + es,      e1 = eb + es + 16;
        bool v0 = e0 < end,     v1 = e1 < end;
        int  si0 = v0 ? csr[e0] : 0;
        int  si1 = v1 ? csr[e1] : 0;
        float iv0 = inv[si0],   iv1 = inv[si1];
        f32x4 fs0 = *(const f32x4*)(f + (size_t)si0 * 16 + c * 4);
        f32x4 fs1 = *(const f32x4*)(f + (size_t)si1 * 16 + c * 4);
        float d0 = fs0.x*fd.x + fs0.y*fd.y + fs0.z*fd.z + fs0.w*fd.w;
        float d1 = fs1.x*fd.x + fs1.y*fd.y + fs1.z*fd.z + fs1.w*fd.w;
        d0 += shflx(d0, 1); d1 += shflx(d1, 1);
        d0 += shflx(d0, 2); d1 += shflx(d1, 2);
        float p0 = v0 ? __expf(bs * iv0 * d0) : 0.f;
        float p1 = v1 ? __expf(bs * iv1 * d1) : 0.f;
        sacc += p0 + p1;
        gacc.x += p0 * fs0.x + p1 * fs1.x;
        gacc.y += p0 * fs0.y + p1 * fs1.y;
        gacc.z += p0 * fs0.z + p1 * fs1.z;
        gacc.w += p0 * fs0.w + p1 * fs1.w;
    }
#pragma unroll
    for (int m = 4; m <= 32; m <<= 1) {
        sacc   += shflx(sacc, m);
        gacc.x += shflx(gacc.x, m); gacc.y += shflx(gacc.y, m);
        gacc.z += shflx(gacc.z, m); gacc.w += shflx(gacc.w, m);
    }
    float denom = sacc + pself + EPS_SM;
    float o[4];
    o[0] = (gacc.x + pself * fd.x) / denom;
    o[1] = (gacc.y + pself * fd.y) / denom;
    o[2] = (gacc.z + pself * fd.z) / denom;
    o[3] = (gacc.w + pself * fd.w) / denom;

    int cc = lane;
    int csafe = cc < 40 ? cc : 0;
    float z = (cc < 40) ? b2s[cc] : 0.f;
#pragma unroll
    for (int kk = 0; kk < 16; ++kk) {
        float fk = __shfl(o[kk & 3], kk >> 2);
        z += fk * w2s[kk * 40 + csafe];
    }
    float zm = (cc < 40) ? z : -INFINITY;
    float m = zm;
    m = fmaxf(m, shflx(m, 1));  m = fmaxf(m, shflx(m, 2));
    m = fmaxf(m, shflx(m, 4));  m = fmaxf(m, shflx(m, 8));
    m = fmaxf(m, shflx(m, 16)); m = fmaxf(m, shflx(m, 32));
    float e = __expf(zm - m);
    float s = e;
    s += shflx(s, 1);  s += shflx(s, 2);
    s += shflx(s, 4);  s += shflx(s, 8);
    s += shflx(s, 16); s += shflx(s, 32);
    if (cc < 40)
        out[(size_t)wid * 40 + cc] = e / s;
}

extern "C" void kernel_launch(void* const* d_in, const int* in_sizes, int n_in,
                              void* d_out, int out_size, void* d_ws, size_t ws_size,
                              hipStream_t stream) {
    const float* x    = (const float*)d_in[0];
    const int*   eidx = (const int*)d_in[1];
    const float* W1   = (const float*)d_in[2];
    const float* b1   = (const float*)d_in[3];
    const float* beta[3] = {(const float*)d_in[4], (const float*)d_in[5],
                            (const float*)d_in[6]};
    const float* W2   = (const float*)d_in[7];
    const float* b2   = (const float*)d_in[8];
    float*       out  = (float*)d_out;

    const int FIN = 512, H = 16;
    int N = in_sizes[0] / FIN;
    int E = in_sizes[1] / 2;
    int NB = (N + BRANGE - 1) >> BSH;

    const int* src = eidx;
    const int* dst = eidx + E;

    int*   csr  = (int*)d_ws;
    int*   degb = csr + (size_t)N * SLOT;
    int*   gcur = degb + N;
    int*   part = gcur + 512;
    float* f0   = (float*)(part + (size_t)NB * BCAP);
    float* f1   = f0 + (size_t)N * H;
    float* inv0 = f1 + (size_t)N * H;
    float* inv1 = inv0 + N;

    hipMemsetAsync(gcur, 0, 512 * 4, stream);
    k_part<<<dim3((E + TILE - 1) / TILE), dim3(1024), 0, stream>>>(src, dst, gcur, part, E, NB);
    k_csr<<<dim3(NB), dim3(1024), 0, stream>>>(part, gcur, csr, degb, N);

    k_gemm1<<<dim3(GEMM_GRID), dim3(256), 0, stream>>>(x, W1, b1, f0, inv0, N);

    k_agnn<<<dim3((N + 3) / 4), dim3(256), 0, stream>>>(
        f0, inv0, degb, csr, beta[0], f1, inv1, N);
    k_agnn<<<dim3((N + 3) / 4), dim3(256), 0, stream>>>(
        f1, inv1, degb, csr, beta[1], f0, inv0, N);
    k_agnn_out<<<dim3((N + 3) / 4), dim3(256), 0, stream>>>(
        f0, inv0, degb, csr, beta[2], W2, b2, out, N);
}

// Round 17
// 329.587 us; speedup vs baseline: 1.1495x; 1.1495x over previous
//
#include <hip/hip_runtime.h>
#include <hip/hip_bf16.h>

#define EPS_NORM 1e-12f
#define EPS_SM   1e-16f
#define SLOT     96        // padded CSR stride; >= any realistic in-degree (Poisson(32))
#define BSH      8         // bucket = 256 consecutive dst nodes
#define BRANGE   256
#define NBMAX    512       // LDS sizing (supports N <= 131072)
#define BCAP     9216      // per-bucket edge capacity: mean 8184, +11 sigma
#define TILE     8192      // edges per partition block
#define GEMM_GRID 512      // persistent gemm blocks (2/CU at 70KB LDS)

typedef float f32x4 __attribute__((ext_vector_type(4)));
__device__ __forceinline__ float shflx(float x, int m) { return __shfl_xor(x, m); }

// ============ pass 1: partition edges into dst-range buckets (coalesced writes) ============
__global__ __launch_bounds__(1024) void k_part(const int* __restrict__ src,
        const int* __restrict__ dst, int* __restrict__ gcur, int* __restrict__ part,
        int E, int NB) {
    __shared__ int h[NBMAX];
    __shared__ int c0[NBMAX];
    __shared__ int lo[NBMAX + 1];
    __shared__ int cur[NBMAX];
    __shared__ int gb[NBMAX];
    __shared__ int stage[TILE];
    __shared__ unsigned short sb[TILE];
    int t = threadIdx.x;
    int tile0 = blockIdx.x * TILE;
    int n = E - tile0; if (n > TILE) n = TILE;

    for (int i = t; i < NBMAX; i += 1024) h[i] = 0;
    __syncthreads();
    for (int i = t; i < n; i += 1024)
        atomicAdd(&h[__builtin_nontemporal_load(&dst[tile0 + i]) >> BSH], 1);
    __syncthreads();
    for (int i = t; i < NBMAX; i += 1024) c0[i] = h[i];
    __syncthreads();
    for (int d = 1; d < NBMAX; d <<= 1) {
        int v = (t < NBMAX && t >= d) ? h[t - d] : 0;
        __syncthreads();
        if (t < NBMAX) h[t] += v;
        __syncthreads();
    }
    if (t < NBMAX) { lo[t] = h[t] - c0[t]; cur[t] = h[t] - c0[t]; }
    if (t == 0) lo[NBMAX] = n;
    __syncthreads();
    for (int i = t; i < NB; i += 1024)
        gb[i] = (c0[i] > 0) ? atomicAdd(&gcur[i], c0[i]) : 0;
    __syncthreads();
    for (int i = t; i < n; i += 1024) {
        int d = __builtin_nontemporal_load(&dst[tile0 + i]);
        int s = __builtin_nontemporal_load(&src[tile0 + i]);
        int b = d >> BSH;
        int p = atomicAdd(&cur[b], 1);
        stage[p] = (s << BSH) | (d & (BRANGE - 1));
        sb[p] = (unsigned short)b;
    }
    __syncthreads();
    for (int i = t; i < n; i += 1024) {
        int b = sb[i];
        int gpos = gb[b] + (i - lo[b]);
        if (gpos < BCAP)
            __builtin_nontemporal_store(stage[i], &part[b * BCAP + gpos]);
    }
}

// ============ pass 2: bucket -> padded CSR (one block per bucket; LDS positions) ============
__global__ __launch_bounds__(1024) void k_csr(const int* __restrict__ part,
        const int* __restrict__ gcur, int* __restrict__ csr, int* __restrict__ deg, int N) {
    __shared__ int cnt[BRANGE];
    int b = blockIdx.x, t = threadIdx.x;
    if (t < BRANGE) cnt[t] = 0;
    __syncthreads();
    int cntE = gcur[b]; if (cntE > BCAP) cntE = BCAP;
    const int* pb = part + b * BCAP;
    int n0 = b << BSH;
    for (int i = t; i < cntE; i += 1024) {
        int v = __builtin_nontemporal_load(&pb[i]);   // streamed once
        int d = v & (BRANGE - 1);
        int s = v >> BSH;
        int p = atomicAdd(&cnt[d], 1);
        if (p < SLOT)
            csr[(size_t)(n0 + d) * SLOT + p] = s;
    }
    __syncthreads();
    if (t < BRANGE && n0 + t < N) deg[n0 + t] = cnt[t];
}

// ======================= h = relu(x @ W1 + b1), + inv-norm of h =======================
// PERSISTENT blocks (grid=512, 2/CU): W1 staged to LDS ONCE; register dbuf x tiles.
__global__ __launch_bounds__(256) void k_gemm1(const float* __restrict__ x,
        const float* __restrict__ W1, const float* __restrict__ b1,
        float* __restrict__ h, float* __restrict__ invn, int N) {
    __shared__ __align__(16) float w1t[16 * 516];
    __shared__ __align__(16) float xs[16 * 516];
    __shared__ float red[4 * 256];
    int t = threadIdx.x;
    int wave = t >> 6, lane = t & 63;
    int i = lane >> 3, j = lane & 7;

    for (int g = t; g < 2048; g += 256) {
        f32x4 v = *(const f32x4*)(W1 + g * 4);
        int k = g >> 2, c0 = (g & 3) * 4;
        w1t[(c0 + 0) * 516 + k] = v.x;
        w1t[(c0 + 1) * 516 + k] = v.y;
        w1t[(c0 + 2) * 516 + k] = v.z;
        w1t[(c0 + 3) * 516 + k] = v.w;
    }

    int ntiles = (N + 15) >> 4;
    int per = (ntiles + GEMM_GRID - 1) / GEMM_GRID;
    int t0 = blockIdx.x * per;
    int t1 = t0 + per; if (t1 > ntiles) t1 = ntiles;
    if (t0 >= t1) return;

    f32x4 rg[8];
    {
        int row0 = t0 << 4;
        const f32x4* gx = (const f32x4*)(x + (size_t)row0 * 512);
#pragma unroll
        for (int jj = 0; jj < 8; ++jj) {
            int idx = t + jj * 256;
            int safe = (row0 + (idx >> 7) < N) ? idx : (idx & 127);
            rg[jj] = gx[safe];
        }
    }

    for (int tt = t0; tt < t1; ++tt) {
        __syncthreads();
#pragma unroll
        for (int jj = 0; jj < 8; ++jj) {
            int idx = t + jj * 256;
            *(f32x4*)(xs + (idx >> 7) * 516 + (idx & 127) * 4) = rg[jj];
        }
        __syncthreads();
        if (tt + 1 < t1) {
            int row0 = (tt + 1) << 4;
            const f32x4* gx = (const f32x4*)(x + (size_t)row0 * 512);
#pragma unroll
            for (int jj = 0; jj < 8; ++jj) {
                int idx = t + jj * 256;
                int safe = (row0 + (idx >> 7) < N) ? idx : (idx & 127);
                rg[jj] = gx[safe];
            }
        }
        const float* xA = xs + i * 516;
        const float* xB = xs + (i + 8) * 516;
        const float* wA = w1t + j * 516;
        const float* wB = w1t + (j + 8) * 516;
        int k0 = wave * 128;
        float acc00 = 0.f, acc01 = 0.f, acc10 = 0.f, acc11 = 0.f;
#pragma unroll 4
        for (int kq = 0; kq < 32; ++kq) {
            int k = k0 + kq * 4;
            f32x4 a = *(const f32x4*)(xA + k);
            f32x4 b = *(const f32x4*)(xB + k);
            f32x4 u = *(const f32x4*)(wA + k);
            f32x4 v = *(const f32x4*)(wB + k);
            acc00 += a.x*u.x + a.y*u.y + a.z*u.z + a.w*u.w;
            acc01 += a.x*v.x + a.y*v.y + a.z*v.z + a.w*v.w;
            acc10 += b.x*u.x + b.y*u.y + b.z*u.z + b.w*u.w;
            acc11 += b.x*v.x + b.y*v.y + b.z*v.z + b.w*v.w;
        }
        red[wave * 256 + i * 16 + j]             = acc00;
        red[wave * 256 + i * 16 + (j + 8)]       = acc01;
        red[wave * 256 + (i + 8) * 16 + j]       = acc10;
        red[wave * 256 + (i + 8) * 16 + (j + 8)] = acc11;
        __syncthreads();

        int r = t >> 4, c = t & 15;
        int rc = r * 16 + c;
        float sum = red[rc] + red[256 + rc] + red[512 + rc] + red[768 + rc];
        int row = (tt << 4) + r;
        float val = fmaxf(sum + b1[c], 0.f);
        if (row < N) h[(size_t)row * 16 + c] = val;
        float ss = val * val;
        ss += shflx(ss, 1); ss += shflx(ss, 2);
        ss += shflx(ss, 4); ss += shflx(ss, 8);
        if (c == 0 && row < N) invn[row] = 1.f / fmaxf(sqrtf(ss), EPS_NORM);
    }
}

// ============== fused AGNN layer: 4 lanes/edge, 16 edges per wave-round ==============
// csr reads are nt: streamed once per layer, must not evict the L2-resident f table.
__global__ __launch_bounds__(256) void k_agnn(const float* __restrict__ f,
        const float* __restrict__ inv, const int* __restrict__ deg,
        const int* __restrict__ csr, const float* __restrict__ beta,
        float* __restrict__ fout, float* __restrict__ invout, int N) {
    int wid = (blockIdx.x * 256 + threadIdx.x) >> 6;
    if (wid >= N) return;
    int lane = threadIdx.x & 63;
    int es = lane >> 2, c = lane & 3;

    const f32x4 fd = *(const f32x4*)(f + (size_t)wid * 16 + c * 4);
    float ivd = inv[wid];
    float b   = beta[0];

    float sd = fd.x*fd.x + fd.y*fd.y + fd.z*fd.z + fd.w*fd.w;
    sd += shflx(sd, 1); sd += shflx(sd, 2);
    float pself = __expf(b * sd * ivd * ivd);
    float bs = b * ivd;

    int dg = deg[wid]; if (dg > SLOT) dg = SLOT;
    int start = wid * SLOT;
    int end   = start + dg;

    float sacc = 0.f;
    f32x4 gacc = {0.f, 0.f, 0.f, 0.f};
    for (int eb = start; eb < end; eb += 16) {
        int  e = eb + es;
        bool v = e < end;
        int  si = v ? __builtin_nontemporal_load(&csr[e]) : 0;
        float iv = inv[si];
        f32x4 fs = *(const f32x4*)(f + (size_t)si * 16 + c * 4);
        float d = fs.x*fd.x + fs.y*fd.y + fs.z*fd.z + fs.w*fd.w;
        d += shflx(d, 1); d += shflx(d, 2);
        float p = v ? __expf(bs * iv * d) : 0.f;
        sacc += p;
        gacc.x += p * fs.x; gacc.y += p * fs.y;
        gacc.z += p * fs.z; gacc.w += p * fs.w;
    }
#pragma unroll
    for (int m = 4; m <= 32; m <<= 1) {
        sacc   += shflx(sacc, m);
        gacc.x += shflx(gacc.x, m); gacc.y += shflx(gacc.y, m);
        gacc.z += shflx(gacc.z, m); gacc.w += shflx(gacc.w, m);
    }
    float denom = sacc + pself + EPS_SM;
    f32x4 o;
    o.x = (gacc.x + pself * fd.x) / denom;
    o.y = (gacc.y + pself * fd.y) / denom;
    o.z = (gacc.z + pself * fd.z) / denom;
    o.w = (gacc.w + pself * fd.w) / denom;

    float ss = o.x*o.x + o.y*o.y + o.z*o.z + o.w*o.w;
    ss += shflx(ss, 1); ss += shflx(ss, 2);

    if (es == 0) {
        *(f32x4*)(fout + (size_t)wid * 16 + c * 4) = o;
        if (c == 0) invout[wid] = 1.f / fmaxf(sqrtf(ss), EPS_NORM);
    }
}

// ===== layer-3 AGNN with fused classifier: out = softmax(agnn(f) @ W2 + b2) =====
__global__ __launch_bounds__(256) void k_agnn_out(const float* __restrict__ f,
        const float* __restrict__ inv, const int* __restrict__ deg,
        const int* __restrict__ csr, const float* __restrict__ beta,
        const float* __restrict__ W2, const float* __restrict__ b2,
        float* __restrict__ out, int N) {
    __shared__ float w2s[16 * 40];
    __shared__ float b2s[40];
    for (int idx = threadIdx.x; idx < 16 * 40; idx += 256) w2s[idx] = W2[idx];
    if (threadIdx.x < 40) b2s[threadIdx.x] = b2[threadIdx.x];
    __syncthreads();

    int wid = (blockIdx.x * 256 + threadIdx.x) >> 6;
    if (wid >= N) return;
    int lane = threadIdx.x & 63;
    int es = lane >> 2, c = lane & 3;

    const f32x4 fd = *(const f32x4*)(f + (size_t)wid * 16 + c * 4);
    float ivd = inv[wid];
    float b   = beta[0];

    float sd = fd.x*fd.x + fd.y*fd.y + fd.z*fd.z + fd.w*fd.w;
    sd += shflx(sd, 1); sd += shflx(sd, 2);
    float pself = __expf(b * sd * ivd * ivd);
    float bs = b * ivd;

    int dg = deg[wid]; if (dg > SLOT) dg = SLOT;
    int start = wid * SLOT;
    int end   = start + dg;

    float sacc = 0.f;
    f32x4 gacc = {0.f, 0.f, 0.f, 0.f};
    for (int eb = start; eb < end; eb += 16) {
        int  e = eb + es;
        bool v = e < end;
        int  si = v ? __builtin_nontemporal_load(&csr[e]) : 0;
        float iv = inv[si];
        f32x4 fs = *(const f32x4*)(f + (size_t)si * 16 + c * 4);
        float d = fs.x*fd.x + fs.y*fd.y + fs.z*fd.z + fs.w*fd.w;
        d += shflx(d, 1); d += shflx(d, 2);
        float p = v ? __expf(bs * iv * d) : 0.f;
        sacc += p;
        gacc.x += p * fs.x; gacc.y += p * fs.y;
        gacc.z += p * fs.z; gacc.w += p * fs.w;
    }
#pragma unroll
    for (int m = 4; m <= 32; m <<= 1) {
        sacc   += shflx(sacc, m);
        gacc.x += shflx(gacc.x, m); gacc.y += shflx(gacc.y, m);
        gacc.z += shflx(gacc.z, m); gacc.w += shflx(gacc.w, m);
    }
    float denom = sacc + pself + EPS_SM;
    float o[4];
    o[0] = (gacc.x + pself * fd.x) / denom;
    o[1] = (gacc.y + pself * fd.y) / denom;
    o[2] = (gacc.z + pself * fd.z) / denom;
    o[3] = (gacc.w + pself * fd.w) / denom;

    int cc = lane;
    int csafe = cc < 40 ? cc : 0;
    float z = (cc < 40) ? b2s[cc] : 0.f;
#pragma unroll
    for (int kk = 0; kk < 16; ++kk) {
        float fk = __shfl(o[kk & 3], kk >> 2);
        z += fk * w2s[kk * 40 + csafe];
    }
    float zm = (cc < 40) ? z : -INFINITY;
    float m = zm;
    m = fmaxf(m, shflx(m, 1));  m = fmaxf(m, shflx(m, 2));
    m = fmaxf(m, shflx(m, 4));  m = fmaxf(m, shflx(m, 8));
    m = fmaxf(m, shflx(m, 16)); m = fmaxf(m, shflx(m, 32));
    float e = __expf(zm - m);
    float s = e;
    s += shflx(s, 1);  s += shflx(s, 2);
    s += shflx(s, 4);  s += shflx(s, 8);
    s += shflx(s, 16); s += shflx(s, 32);
    if (cc < 40)
        out[(size_t)wid * 40 + cc] = e / s;
}

extern "C" void kernel_launch(void* const* d_in, const int* in_sizes, int n_in,
                              void* d_out, int out_size, void* d_ws, size_t ws_size,
                              hipStream_t stream) {
    const float* x    = (const float*)d_in[0];
    const int*   eidx = (const int*)d_in[1];
    const float* W1   = (const float*)d_in[2];
    const float* b1   = (const float*)d_in[3];
    const float* beta[3] = {(const float*)d_in[4], (const float*)d_in[5],
                            (const float*)d_in[6]};
    const float* W2   = (const float*)d_in[7];
    const float* b2   = (const float*)d_in[8];
    float*       out  = (float*)d_out;

    const int FIN = 512, H = 16;
    int N = in_sizes[0] / FIN;
    int E = in_sizes[1] / 2;
    int NB = (N + BRANGE - 1) >> BSH;

    const int* src = eidx;
    const int* dst = eidx + E;

    int*   csr  = (int*)d_ws;
    int*   degb = csr + (size_t)N * SLOT;
    int*   gcur = degb + N;
    int*   part = gcur + 512;
    float* f0   = (float*)(part + (size_t)NB * BCAP);
    float* f1   = f0 + (size_t)N * H;
    float* inv0 = f1 + (size_t)N * H;
    float* inv1 = inv0 + N;

    hipMemsetAsync(gcur, 0, 512 * 4, stream);
    k_part<<<dim3((E + TILE - 1) / TILE), dim3(1024), 0, stream>>>(src, dst, gcur, part, E, NB);
    k_csr<<<dim3(NB), dim3(1024), 0, stream>>>(part, gcur, csr, degb, N);

    k_gemm1<<<dim3(GEMM_GRID), dim3(256), 0, stream>>>(x, W1, b1, f0, inv0, N);

    k_agnn<<<dim3((N + 3) / 4), dim3(256), 0, stream>>>(
        f0, inv0, degb, csr, beta[0], f1, inv1, N);
    k_agnn<<<dim3((N + 3) / 4), dim3(256), 0, stream>>>(
        f1, inv1, degb, csr, beta[1], f0, inv0, N);
    k_agnn_out<<<dim3((N + 3) / 4), dim3(256), 0, stream>>>(
        f0, inv0, degb, csr, beta[2], W2, b2, out, N);
}

// Round 18
// 297.877 us; speedup vs baseline: 1.2718x; 1.1065x over previous
//
#include <hip/hip_runtime.h>
#include <hip/hip_bf16.h>

#define EPS_NORM 1e-12f
#define EPS_SM   1e-16f
#define SLOT     96        // padded CSR stride; >= any realistic in-degree (Poisson(32))
#define BSH      8         // bucket = 256 consecutive dst nodes
#define BRANGE   256
#define NBMAX    512       // LDS sizing (supports N <= 131072)
#define BCAP     9216      // per-bucket edge capacity: mean 8184, +11 sigma
#define TILE     8192      // edges per partition block
#define GEMM_GRID 512      // persistent gemm blocks (2/CU at 70KB LDS)

typedef float f32x4 __attribute__((ext_vector_type(4)));
__device__ __forceinline__ float shflx(float x, int m) { return __shfl_xor(x, m); }

// ============ pass 1: partition edges into dst-range buckets (coalesced writes) ============
__global__ __launch_bounds__(1024) void k_part(const int* __restrict__ src,
        const int* __restrict__ dst, int* __restrict__ gcur, int* __restrict__ part,
        int E, int NB) {
    __shared__ int h[NBMAX];
    __shared__ int c0[NBMAX];
    __shared__ int lo[NBMAX + 1];
    __shared__ int cur[NBMAX];
    __shared__ int gb[NBMAX];
    __shared__ int stage[TILE];
    __shared__ unsigned short sb[TILE];
    int t = threadIdx.x;
    int tile0 = blockIdx.x * TILE;
    int n = E - tile0; if (n > TILE) n = TILE;

    for (int i = t; i < NBMAX; i += 1024) h[i] = 0;
    __syncthreads();
    for (int i = t; i < n; i += 1024)
        atomicAdd(&h[dst[tile0 + i] >> BSH], 1);
    __syncthreads();
    for (int i = t; i < NBMAX; i += 1024) c0[i] = h[i];
    __syncthreads();
    for (int d = 1; d < NBMAX; d <<= 1) {
        int v = (t < NBMAX && t >= d) ? h[t - d] : 0;
        __syncthreads();
        if (t < NBMAX) h[t] += v;
        __syncthreads();
    }
    if (t < NBMAX) { lo[t] = h[t] - c0[t]; cur[t] = h[t] - c0[t]; }
    if (t == 0) lo[NBMAX] = n;
    __syncthreads();
    for (int i = t; i < NB; i += 1024)
        gb[i] = (c0[i] > 0) ? atomicAdd(&gcur[i], c0[i]) : 0;
    __syncthreads();
    for (int i = t; i < n; i += 1024) {
        int d = dst[tile0 + i];
        int s = src[tile0 + i];
        int b = d >> BSH;
        int p = atomicAdd(&cur[b], 1);
        stage[p] = (s << BSH) | (d & (BRANGE - 1));
        sb[p] = (unsigned short)b;
    }
    __syncthreads();
    for (int i = t; i < n; i += 1024) {
        int b = sb[i];
        int gpos = gb[b] + (i - lo[b]);
        if (gpos < BCAP)
            part[b * BCAP + gpos] = stage[i];
    }
}

// ============ pass 2: bucket -> padded CSR (one block per bucket; LDS positions) ============
__global__ __launch_bounds__(1024) void k_csr(const int* __restrict__ part,
        const int* __restrict__ gcur, int* __restrict__ csr, int* __restrict__ deg, int N) {
    __shared__ int cnt[BRANGE];
    int b = blockIdx.x, t = threadIdx.x;
    if (t < BRANGE) cnt[t] = 0;
    __syncthreads();
    int cntE = gcur[b]; if (cntE > BCAP) cntE = BCAP;
    const int* pb = part + b * BCAP;
    int n0 = b << BSH;
    for (int i = t; i < cntE; i += 1024) {
        int v = pb[i];
        int d = v & (BRANGE - 1);
        int s = v >> BSH;
        int p = atomicAdd(&cnt[d], 1);
        if (p < SLOT)
            csr[(size_t)(n0 + d) * SLOT + p] = s;
    }
    __syncthreads();
    if (t < BRANGE && n0 + t < N) deg[n0 + t] = cnt[t];
}

// ======================= h = relu(x @ W1 + b1), + inv-norm of h =======================
// PERSISTENT blocks (grid=512, 2/CU): W1 staged to LDS ONCE; register dbuf x tiles.
__global__ __launch_bounds__(256) void k_gemm1(const float* __restrict__ x,
        const float* __restrict__ W1, const float* __restrict__ b1,
        float* __restrict__ h, float* __restrict__ invn, int N) {
    __shared__ __align__(16) float w1t[16 * 516];
    __shared__ __align__(16) float xs[16 * 516];
    __shared__ float red[4 * 256];
    int t = threadIdx.x;
    int wave = t >> 6, lane = t & 63;
    int i = lane >> 3, j = lane & 7;

    for (int g = t; g < 2048; g += 256) {
        f32x4 v = *(const f32x4*)(W1 + g * 4);
        int k = g >> 2, c0 = (g & 3) * 4;
        w1t[(c0 + 0) * 516 + k] = v.x;
        w1t[(c0 + 1) * 516 + k] = v.y;
        w1t[(c0 + 2) * 516 + k] = v.z;
        w1t[(c0 + 3) * 516 + k] = v.w;
    }

    int ntiles = (N + 15) >> 4;
    int per = (ntiles + GEMM_GRID - 1) / GEMM_GRID;
    int t0 = blockIdx.x * per;
    int t1 = t0 + per; if (t1 > ntiles) t1 = ntiles;
    if (t0 >= t1) return;

    f32x4 rg[8];
    {
        int row0 = t0 << 4;
        const f32x4* gx = (const f32x4*)(x + (size_t)row0 * 512);
#pragma unroll
        for (int jj = 0; jj < 8; ++jj) {
            int idx = t + jj * 256;
            int safe = (row0 + (idx >> 7) < N) ? idx : (idx & 127);
            rg[jj] = gx[safe];
        }
    }

    for (int tt = t0; tt < t1; ++tt) {
        __syncthreads();
#pragma unroll
        for (int jj = 0; jj < 8; ++jj) {
            int idx = t + jj * 256;
            *(f32x4*)(xs + (idx >> 7) * 516 + (idx & 127) * 4) = rg[jj];
        }
        __syncthreads();
        if (tt + 1 < t1) {
            int row0 = (tt + 1) << 4;
            const f32x4* gx = (const f32x4*)(x + (size_t)row0 * 512);
#pragma unroll
            for (int jj = 0; jj < 8; ++jj) {
                int idx = t + jj * 256;
                int safe = (row0 + (idx >> 7) < N) ? idx : (idx & 127);
                rg[jj] = gx[safe];
            }
        }
        const float* xA = xs + i * 516;
        const float* xB = xs + (i + 8) * 516;
        const float* wA = w1t + j * 516;
        const float* wB = w1t + (j + 8) * 516;
        int k0 = wave * 128;
        float acc00 = 0.f, acc01 = 0.f, acc10 = 0.f, acc11 = 0.f;
#pragma unroll 4
        for (int kq = 0; kq < 32; ++kq) {
            int k = k0 + kq * 4;
            f32x4 a = *(const f32x4*)(xA + k);
            f32x4 b = *(const f32x4*)(xB + k);
            f32x4 u = *(const f32x4*)(wA + k);
            f32x4 v = *(const f32x4*)(wB + k);
            acc00 += a.x*u.x + a.y*u.y + a.z*u.z + a.w*u.w;
            acc01 += a.x*v.x + a.y*v.y + a.z*v.z + a.w*v.w;
            acc10 += b.x*u.x + b.y*u.y + b.z*u.z + b.w*u.w;
            acc11 += b.x*v.x + b.y*v.y + b.z*v.z + b.w*v.w;
        }
        red[wave * 256 + i * 16 + j]             = acc00;
        red[wave * 256 + i * 16 + (j + 8)]       = acc01;
        red[wave * 256 + (i + 8) * 16 + j]       = acc10;
        red[wave * 256 + (i + 8) * 16 + (j + 8)] = acc11;
        __syncthreads();

        int r = t >> 4, c = t & 15;
        int rc = r * 16 + c;
        float sum = red[rc] + red[256 + rc] + red[512 + rc] + red[768 + rc];
        int row = (tt << 4) + r;
        float val = fmaxf(sum + b1[c], 0.f);
        if (row < N) h[(size_t)row * 16 + c] = val;
        float ss = val * val;
        ss += shflx(ss, 1); ss += shflx(ss, 2);
        ss += shflx(ss, 4); ss += shflx(ss, 8);
        if (c == 0 && row < N) invn[row] = 1.f / fmaxf(sqrtf(ss), EPS_NORM);
    }
}

// ============== fused AGNN layer: 4 lanes/edge, 16 edges per wave-round ==============
__global__ __launch_bounds__(256) void k_agnn(const float* __restrict__ f,
        const float* __restrict__ inv, const int* __restrict__ deg,
        const int* __restrict__ csr, const float* __restrict__ beta,
        float* __restrict__ fout, float* __restrict__ invout, int N) {
    int wid = (blockIdx.x * 256 + threadIdx.x) >> 6;
    if (wid >= N) return;
    int lane = threadIdx.x & 63;
    int es = lane >> 2, c = lane & 3;

    const f32x4 fd = *(const f32x4*)(f + (size_t)wid * 16 + c * 4);
    float ivd = inv[wid];
    float b   = beta[0];

    float sd = fd.x*fd.x + fd.y*fd.y + fd.z*fd.z + fd.w*fd.w;
    sd += shflx(sd, 1); sd += shflx(sd, 2);
    float pself = __expf(b * sd * ivd * ivd);
    float bs = b * ivd;

    int dg = deg[wid]; if (dg > SLOT) dg = SLOT;
    int start = wid * SLOT;
    int end   = start + dg;

    float sacc = 0.f;
    f32x4 gacc = {0.f, 0.f, 0.f, 0.f};
    for (int eb = start; eb < end; eb += 16) {
        int  e = eb + es;
        bool v = e < end;
        int  si = v ? csr[e] : 0;
        float iv = inv[si];
        f32x4 fs = *(const f32x4*)(f + (size_t)si * 16 + c * 4);
        float d = fs.x*fd.x + fs.y*fd.y + fs.z*fd.z + fs.w*fd.w;
        d += shflx(d, 1); d += shflx(d, 2);
        float p = v ? __expf(bs * iv * d) : 0.f;
        sacc += p;
        gacc.x += p * fs.x; gacc.y += p * fs.y;
        gacc.z += p * fs.z; gacc.w += p * fs.w;
    }
#pragma unroll
    for (int m = 4; m <= 32; m <<= 1) {
        sacc   += shflx(sacc, m);
        gacc.x += shflx(gacc.x, m); gacc.y += shflx(gacc.y, m);
        gacc.z += shflx(gacc.z, m); gacc.w += shflx(gacc.w, m);
    }
    float denom = sacc + pself + EPS_SM;
    f32x4 o;
    o.x = (gacc.x + pself * fd.x) / denom;
    o.y = (gacc.y + pself * fd.y) / denom;
    o.z = (gacc.z + pself * fd.z) / denom;
    o.w = (gacc.w + pself * fd.w) / denom;

    float ss = o.x*o.x + o.y*o.y + o.z*o.z + o.w*o.w;
    ss += shflx(ss, 1); ss += shflx(ss, 2);

    if (es == 0) {
        *(f32x4*)(fout + (size_t)wid * 16 + c * 4) = o;
        if (c == 0) invout[wid] = 1.f / fmaxf(sqrtf(ss), EPS_NORM);
    }
}

// ===== layer-3 AGNN with fused classifier: out = softmax(agnn(f) @ W2 + b2) =====
__global__ __launch_bounds__(256) void k_agnn_out(const float* __restrict__ f,
        const float* __restrict__ inv, const int* __restrict__ deg,
        const int* __restrict__ csr, const float* __restrict__ beta,
        const float* __restrict__ W2, const float* __restrict__ b2,
        float* __restrict__ out, int N) {
    __shared__ float w2s[16 * 40];
    __shared__ float b2s[40];
    for (int idx = threadIdx.x; idx < 16 * 40; idx += 256) w2s[idx] = W2[idx];
    if (threadIdx.x < 40) b2s[threadIdx.x] = b2[threadIdx.x];
    __syncthreads();

    int wid = (blockIdx.x * 256 + threadIdx.x) >> 6;
    if (wid >= N) return;
    int lane = threadIdx.x & 63;
    int es = lane >> 2, c = lane & 3;

    const f32x4 fd = *(const f32x4*)(f + (size_t)wid * 16 + c * 4);
    float ivd = inv[wid];
    float b   = beta[0];

    float sd = fd.x*fd.x + fd.y*fd.y + fd.z*fd.z + fd.w*fd.w;
    sd += shflx(sd, 1); sd += shflx(sd, 2);
    float pself = __expf(b * sd * ivd * ivd);
    float bs = b * ivd;

    int dg = deg[wid]; if (dg > SLOT) dg = SLOT;
    int start = wid * SLOT;
    int end   = start + dg;

    float sacc = 0.f;
    f32x4 gacc = {0.f, 0.f, 0.f, 0.f};
    for (int eb = start; eb < end; eb += 16) {
        int  e = eb + es;
        bool v = e < end;
        int  si = v ? csr[e] : 0;
        float iv = inv[si];
        f32x4 fs = *(const f32x4*)(f + (size_t)si * 16 + c * 4);
        float d = fs.x*fd.x + fs.y*fd.y + fs.z*fd.z + fs.w*fd.w;
        d += shflx(d, 1); d += shflx(d, 2);
        float p = v ? __expf(bs * iv * d) : 0.f;
        sacc += p;
        gacc.x += p * fs.x; gacc.y += p * fs.y;
        gacc.z += p * fs.z; gacc.w += p * fs.w;
    }
#pragma unroll
    for (int m = 4; m <= 32; m <<= 1) {
        sacc   += shflx(sacc, m);
        gacc.x += shflx(gacc.x, m); gacc.y += shflx(gacc.y, m);
        gacc.z += shflx(gacc.z, m); gacc.w += shflx(gacc.w, m);
    }
    float denom = sacc + pself + EPS_SM;
    float o[4];
    o[0] = (gacc.x + pself * fd.x) / denom;
    o[1] = (gacc.y + pself * fd.y) / denom;
    o[2] = (gacc.z + pself * fd.z) / denom;
    o[3] = (gacc.w + pself * fd.w) / denom;

    int cc = lane;
    int csafe = cc < 40 ? cc : 0;
    float z = (cc < 40) ? b2s[cc] : 0.f;
#pragma unroll
    for (int kk = 0; kk < 16; ++kk) {
        float fk = __shfl(o[kk & 3], kk >> 2);
        z += fk * w2s[kk * 40 + csafe];
    }
    float zm = (cc < 40) ? z : -INFINITY;
    float m = zm;
    m = fmaxf(m, shflx(m, 1));  m = fmaxf(m, shflx(m, 2));
    m = fmaxf(m, shflx(m, 4));  m = fmaxf(m, shflx(m, 8));
    m = fmaxf(m, shflx(m, 16)); m = fmaxf(m, shflx(m, 32));
    float e = __expf(zm - m);
    float s = e;
    s += shflx(s, 1);  s += shflx(s, 2);
    s += shflx(s, 4);  s += shflx(s, 8);
    s += shflx(s, 16); s += shflx(s, 32);
    if (cc < 40)
        out[(size_t)wid * 40 + cc] = e / s;
}

extern "C" void kernel_launch(void* const* d_in, const int* in_sizes, int n_in,
                              void* d_out, int out_size, void* d_ws, size_t ws_size,
                              hipStream_t stream) {
    const float* x    = (const float*)d_in[0];
    const int*   eidx = (const int*)d_in[1];
    const float* W1   = (const float*)d_in[2];
    const float* b1   = (const float*)d_in[3];
    const float* beta[3] = {(const float*)d_in[4], (const float*)d_in[5],
                            (const float*)d_in[6]};
    const float* W2   = (const float*)d_in[7];
    const float* b2   = (const float*)d_in[8];
    float*       out  = (float*)d_out;

    const int FIN = 512, H = 16;
    int N = in_sizes[0] / FIN;
    int E = in_sizes[1] / 2;
    int NB = (N + BRANGE - 1) >> BSH;

    const int* src = eidx;
    const int* dst = eidx + E;

    int*   csr  = (int*)d_ws;
    int*   degb = csr + (size_t)N * SLOT;
    int*   gcur = degb + N;
    int*   part = gcur + 512;
    float* f0   = (float*)(part + (size_t)NB * BCAP);
    float* f1   = f0 + (size_t)N * H;
    float* inv0 = f1 + (size_t)N * H;
    float* inv1 = inv0 + N;

    hipMemsetAsync(gcur, 0, 512 * 4, stream);
    k_part<<<dim3((E + TILE - 1) / TILE), dim3(1024), 0, stream>>>(src, dst, gcur, part, E, NB);
    k_csr<<<dim3(NB), dim3(1024), 0, stream>>>(part, gcur, csr, degb, N);

    k_gemm1<<<dim3(GEMM_GRID), dim3(256), 0, stream>>>(x, W1, b1, f0, inv0, N);

    k_agnn<<<dim3((N + 3) / 4), dim3(256), 0, stream>>>(
        f0, inv0, degb, csr, beta[0], f1, inv1, N);
    k_agnn<<<dim3((N + 3) / 4), dim3(256), 0, stream>>>(
        f1, inv1, degb, csr, beta[1], f0, inv0, N);
    k_agnn_out<<<dim3((N + 3) / 4), dim3(256), 0, stream>>>(
        f0, inv0, degb, csr, beta[2], W2, b2, out, N);
}